// Round 2
// baseline (607.359 us; speedup 1.0000x reference)
//
#include <hip/hip_runtime.h>
#include <cmath>

// DarwinianRouter: fused L2-normalize + x_norm @ sig^T * 5 + top-8 + softplus.
// Round 2: split-K (S splits) to fix occupancy (was 1 wave/SIMD, 11%).
//   gemm_partial: grid (256, S) blocks, 4x4 microtile, writes raw partial dots
//     P[s][e][tok] (reducer-coalesced layout) + partial sumsq SS[s][tok].
//   reduce_topk: 1024 blocks x 64 thr; sums partials in fixed s-order,
//     applies 5/||x||, top-8 (strict '>' = lowest index on ties), softplus.
// Indices must match fp32 reference exactly => fp32 blocked accumulation.

#define N_TOKENS 16384
#define DIM      4096
#define NE       64
#define TOPK     8
#define TM       64      // tokens per gemm block
#define BK       64      // K per LDS tile
#define LSTR     65      // LDS row stride for gemm tiles
#define RSTR     64      // epilogue transpose stride (16B-aligned float4 reads)
#define DSTR     68      // reducer res stride (16B-aligned, 2-way-free topk)
#define SCALE    5.0f
#define EPS      1e-12f

__launch_bounds__(256, 4)
__global__ void gemm_partial(const float* __restrict__ x,
                             const float* __restrict__ sig,
                             float* __restrict__ P,    // [S][NE][N_TOKENS]
                             float* __restrict__ SS,   // [S][N_TOKENS]
                             int S) {
    __shared__ float xs[TM * LSTR];
    __shared__ float ss[NE * LSTR];

    const int t    = threadIdx.x;
    const int tok0 = blockIdx.x * TM;
    const int s    = blockIdx.y;
    const int KC   = DIM / S;        // K-chunk per split
    const int k0b  = s * KC;
    const int nt   = KC / BK;

    const int lr = t >> 4;           // loader row 0..15 (+16m)
    const int lc = (t & 15) << 2;    // loader 16B column
    const int tx = t & 15;           // compute: expert lane
    const int ty = t >> 4;           // compute: token group

    const float* xg = x + (size_t)tok0 * DIM;

    float acc[4][4];
#pragma unroll
    for (int i = 0; i < 4; ++i)
#pragma unroll
        for (int j = 0; j < 4; ++j) acc[i][j] = 0.f;
    float sq[4] = {0.f, 0.f, 0.f, 0.f};

    float4 px[4], ps[4];
#pragma unroll
    for (int m = 0; m < 4; ++m) {
        px[m] = *(const float4*)(xg  + (size_t)(lr + 16 * m) * DIM + k0b + lc);
        ps[m] = *(const float4*)(sig + (size_t)(lr + 16 * m) * DIM + k0b + lc);
    }

    for (int kt = 0; kt < nt; ++kt) {
#pragma unroll
        for (int m = 0; m < 4; ++m) {
            *(float4*)(xs + (lr + 16 * m) * LSTR + lc) = px[m];
            *(float4*)(ss + (lr + 16 * m) * LSTR + lc) = ps[m];
            sq[m] = fmaf(px[m].x, px[m].x, sq[m]);
            sq[m] = fmaf(px[m].y, px[m].y, sq[m]);
            sq[m] = fmaf(px[m].z, px[m].z, sq[m]);
            sq[m] = fmaf(px[m].w, px[m].w, sq[m]);
        }
        __syncthreads();

        if (kt + 1 < nt) {
            const int k0 = k0b + (kt + 1) * BK;
#pragma unroll
            for (int m = 0; m < 4; ++m) {
                px[m] = *(const float4*)(xg  + (size_t)(lr + 16 * m) * DIM + k0 + lc);
                ps[m] = *(const float4*)(sig + (size_t)(lr + 16 * m) * DIM + k0 + lc);
            }
        }

        float tacc[4][4];
#pragma unroll
        for (int i = 0; i < 4; ++i)
#pragma unroll
            for (int j = 0; j < 4; ++j) tacc[i][j] = 0.f;

#pragma unroll
        for (int k4 = 0; k4 < BK; k4 += 4) {
            float4 xv[4], sv[4];
#pragma unroll
            for (int i = 0; i < 4; ++i)
                xv[i] = *(const float4*)(xs + (4 * ty + i) * LSTR + k4);
#pragma unroll
            for (int j = 0; j < 4; ++j)
                sv[j] = *(const float4*)(ss + (tx + 16 * j) * LSTR + k4);
#pragma unroll
            for (int i = 0; i < 4; ++i)
#pragma unroll
                for (int j = 0; j < 4; ++j) {
                    tacc[i][j] = fmaf(xv[i].x, sv[j].x, tacc[i][j]);
                    tacc[i][j] = fmaf(xv[i].y, sv[j].y, tacc[i][j]);
                    tacc[i][j] = fmaf(xv[i].z, sv[j].z, tacc[i][j]);
                    tacc[i][j] = fmaf(xv[i].w, sv[j].w, tacc[i][j]);
                }
        }
#pragma unroll
        for (int i = 0; i < 4; ++i)
#pragma unroll
            for (int j = 0; j < 4; ++j) acc[i][j] += tacc[i][j];
        __syncthreads();
    }

    // partial sumsq: reduce across the 16 lanes sharing each loader row
#pragma unroll
    for (int m = 0; m < 4; ++m) {
        float v = sq[m];
        v += __shfl_xor(v, 1);
        v += __shfl_xor(v, 2);
        v += __shfl_xor(v, 4);
        v += __shfl_xor(v, 8);
        if ((t & 15) == 0)
            SS[(size_t)s * N_TOKENS + tok0 + lr + 16 * m] = v;
    }

    // transpose partial dots into LDS as [e][tok] (stride 64: 16B-aligned
    // float4 reads; bank conflicts here are once-per-block, negligible)
#pragma unroll
    for (int i = 0; i < 4; ++i)
#pragma unroll
        for (int j = 0; j < 4; ++j)
            xs[(tx + 16 * j) * RSTR + 4 * ty + i] = acc[i][j];
    __syncthreads();

    // coalesced write of P[s][e][tok0..tok0+63]
#pragma unroll
    for (int r = 0; r < 4; ++r) {
        const int idx = r * 256 + t;
        const int e   = idx >> 4;
        const int c   = idx & 15;
        const float4 v = *(const float4*)(xs + e * RSTR + 4 * c);
        *(float4*)(P + ((size_t)(s * NE + e)) * N_TOKENS + tok0 + 4 * c) = v;
    }
}

__launch_bounds__(64)
__global__ void reduce_topk(const float* __restrict__ P,
                            const float* __restrict__ SS,
                            float* __restrict__ outW,
                            float* __restrict__ outI,
                            float* __restrict__ outR,
                            int S) {
    __shared__ float res[16 * DSTR];
    __shared__ float scl[16];

    const int t    = threadIdx.x;
    const int tok0 = blockIdx.x * 16;

    if (t < 16) {
        float q = 0.f;
        for (int s = 0; s < S; ++s)
            q += SS[(size_t)s * N_TOKENS + tok0 + t];
        scl[t] = SCALE / fmaxf(sqrtf(q), EPS);
    }
    __syncthreads();

    const int tl = t & 15;          // token lane
    const int e0 = (t >> 4) * 16;   // expert group
    const float sc = scl[tl];
#pragma unroll
    for (int ei = 0; ei < 16; ++ei) {
        const int e = e0 + ei;
        float a = 0.f;
#pragma unroll 8
        for (int s = 0; s < S; ++s)
            a += P[((size_t)(s * NE + e)) * N_TOKENS + tok0 + tl];
        res[tl * DSTR + e] = a * sc;
    }
    __syncthreads();

    // coalesced resonance write (block's region is contiguous)
    float* dst = outR + (size_t)blockIdx.x * 16 * NE;
#pragma unroll
    for (int r = 0; r < 4; ++r) {
        const int f4 = r * 64 + t;
        const int tk = f4 >> 4;
        const int e4 = (f4 & 15) << 2;
        *(float4*)(dst + (size_t)f4 * 4) = *(const float4*)(res + tk * DSTR + e4);
    }
    __syncthreads();

    // top-8 per token (strict '>' => lowest index on ties, = jax.lax.top_k)
    if (t < 16) {
        float* row = res + t * DSTR;
        const size_t ob = (size_t)(tok0 + t) * TOPK;
#pragma unroll 1
        for (int m = 0; m < TOPK; ++m) {
            float best = -__builtin_inff();
            int bi = 0;
#pragma unroll 1
            for (int e = 0; e < NE; ++e) {
                const float v = row[e];
                if (v > best) { best = v; bi = e; }
            }
            row[bi] = -__builtin_inff();
            outW[ob + m] = log1pf(expf(best));
            outI[ob + m] = (float)bi;
        }
    }
}

// ---- fallback (round-1 monolithic) in case ws_size is too small ----
__launch_bounds__(256)
__global__ void router_mono(const float* __restrict__ x,
                            const float* __restrict__ sig,
                            float* __restrict__ outW,
                            float* __restrict__ outI,
                            float* __restrict__ outR) {
    __shared__ float xs[TM * LSTR];
    __shared__ float ss[NE * LSTR];
    __shared__ float scales[TM];

    const int t    = threadIdx.x;
    const int tok0 = blockIdx.x * TM;
    const int lr = t >> 4;
    const int lc = (t & 15) << 2;
    const int tx = t & 15;
    const int ty = t >> 4;
    const float* xg = x + (size_t)tok0 * DIM;

    float acc[4][4];
#pragma unroll
    for (int i = 0; i < 4; ++i)
#pragma unroll
        for (int j = 0; j < 4; ++j) acc[i][j] = 0.f;
    float sq[4] = {0.f, 0.f, 0.f, 0.f};

    float4 px[4], ps[4];
#pragma unroll
    for (int m = 0; m < 4; ++m) {
        px[m] = *(const float4*)(xg  + (size_t)(lr + 16 * m) * DIM + lc);
        ps[m] = *(const float4*)(sig + (size_t)(lr + 16 * m) * DIM + lc);
    }
    for (int kt = 0; kt < DIM / BK; ++kt) {
#pragma unroll
        for (int m = 0; m < 4; ++m) {
            *(float4*)(xs + (lr + 16 * m) * LSTR + lc) = px[m];
            *(float4*)(ss + (lr + 16 * m) * LSTR + lc) = ps[m];
            sq[m] = fmaf(px[m].x, px[m].x, sq[m]);
            sq[m] = fmaf(px[m].y, px[m].y, sq[m]);
            sq[m] = fmaf(px[m].z, px[m].z, sq[m]);
            sq[m] = fmaf(px[m].w, px[m].w, sq[m]);
        }
        __syncthreads();
        if (kt + 1 < DIM / BK) {
            const int k0 = (kt + 1) * BK;
#pragma unroll
            for (int m = 0; m < 4; ++m) {
                px[m] = *(const float4*)(xg  + (size_t)(lr + 16 * m) * DIM + k0 + lc);
                ps[m] = *(const float4*)(sig + (size_t)(lr + 16 * m) * DIM + k0 + lc);
            }
        }
        float tacc[4][4];
#pragma unroll
        for (int i = 0; i < 4; ++i)
#pragma unroll
            for (int j = 0; j < 4; ++j) tacc[i][j] = 0.f;
#pragma unroll
        for (int k4 = 0; k4 < BK; k4 += 4) {
            float4 xv[4], sv[4];
#pragma unroll
            for (int i = 0; i < 4; ++i)
                xv[i] = *(const float4*)(xs + (4 * ty + i) * LSTR + k4);
#pragma unroll
            for (int j = 0; j < 4; ++j)
                sv[j] = *(const float4*)(ss + (tx + 16 * j) * LSTR + k4);
#pragma unroll
            for (int i = 0; i < 4; ++i)
#pragma unroll
                for (int j = 0; j < 4; ++j) {
                    tacc[i][j] = fmaf(xv[i].x, sv[j].x, tacc[i][j]);
                    tacc[i][j] = fmaf(xv[i].y, sv[j].y, tacc[i][j]);
                    tacc[i][j] = fmaf(xv[i].z, sv[j].z, tacc[i][j]);
                    tacc[i][j] = fmaf(xv[i].w, sv[j].w, tacc[i][j]);
                }
        }
#pragma unroll
        for (int i = 0; i < 4; ++i)
#pragma unroll
            for (int j = 0; j < 4; ++j) acc[i][j] += tacc[i][j];
        __syncthreads();
    }
#pragma unroll
    for (int m = 0; m < 4; ++m) {
        float v = sq[m];
        v += __shfl_xor(v, 1);
        v += __shfl_xor(v, 2);
        v += __shfl_xor(v, 4);
        v += __shfl_xor(v, 8);
        if ((t & 15) == 0) scales[lr + 16 * m] = v;
    }
    __syncthreads();
    if (t < TM) scales[t] = SCALE / fmaxf(sqrtf(scales[t]), EPS);
    __syncthreads();
    float* res = xs;
#pragma unroll
    for (int i = 0; i < 4; ++i) {
        const int tok = 4 * ty + i;
        const float s = scales[tok];
#pragma unroll
        for (int j = 0; j < 4; ++j) {
            const int e = tx + 16 * j;
            const float r = acc[i][j] * s;
            outR[(size_t)(tok0 + tok) * NE + e] = r;
            res[tok * 65 + e] = r;
        }
    }
    __syncthreads();
    if (t < TM) {
        float* row = res + t * 65;
        const size_t ob = (size_t)(tok0 + t) * TOPK;
#pragma unroll 1
        for (int m = 0; m < TOPK; ++m) {
            float best = -__builtin_inff();
            int bi = 0;
#pragma unroll 1
            for (int e = 0; e < NE; ++e) {
                const float v = row[e];
                if (v > best) { best = v; bi = e; }
            }
            row[bi] = -__builtin_inff();
            outW[ob + m] = log1pf(expf(best));
            outI[ob + m] = (float)bi;
        }
    }
}

extern "C" void kernel_launch(void* const* d_in, const int* in_sizes, int n_in,
                              void* d_out, int out_size, void* d_ws, size_t ws_size,
                              hipStream_t stream) {
    const float* x   = (const float*)d_in[0];
    const float* sig = (const float*)d_in[1];
    float* out  = (float*)d_out;
    float* outW = out;
    float* outI = out + (size_t)N_TOKENS * TOPK;
    float* outR = out + (size_t)N_TOKENS * TOPK * 2;

    const size_t per_split_f = (size_t)NE * N_TOKENS + N_TOKENS; // P row + SS row (floats)
    int S = 8;
    while (S > 1 && S * per_split_f * sizeof(float) > ws_size) S >>= 1;

    if (S * per_split_f * sizeof(float) <= ws_size) {
        float* P  = (float*)d_ws;
        float* SS = P + (size_t)S * NE * N_TOKENS;
        dim3 g1(N_TOKENS / TM, S);
        gemm_partial<<<g1, 256, 0, stream>>>(x, sig, P, SS, S);
        reduce_topk<<<N_TOKENS / 16, 64, 0, stream>>>(P, SS, outW, outI, outR, S);
    } else {
        router_mono<<<N_TOKENS / TM, 256, 0, stream>>>(x, sig, outW, outI, outR);
    }
}

// Round 3
// 605.649 us; speedup vs baseline: 1.0028x; 1.0028x over previous
//
#include <hip/hip_runtime.h>
#include <cmath>

// DarwinianRouter: fused L2-normalize + x_norm @ sig^T * 5 + top-8 + softplus.
// Round 3: split-K structure from round 2, but ALL LDS strides back to 68
// (16B-aligned => ds_read_b128, and 68*r = 4r mod 32 => 2-way bank aliasing
// which is free per m136). Round 2's stride 65/64 scalarized the LDS reads
// and caused 6M bank conflicts -> LDS-pipe-bound at 320us regardless of
// occupancy.
// Indices must match fp32 reference exactly => fp32 blocked accumulation.

#define N_TOKENS 16384
#define DIM      4096
#define NE       64
#define TOPK     8
#define TM       64      // tokens per gemm block
#define BK       64      // K per LDS tile
#define LSTR     68      // LDS row stride everywhere (aligned + conflict-free)
#define SCALE    5.0f
#define EPS      1e-12f

__launch_bounds__(256, 4)
__global__ void gemm_partial(const float* __restrict__ x,
                             const float* __restrict__ sig,
                             float* __restrict__ P,    // [S][NE][N_TOKENS]
                             float* __restrict__ SS,   // [S][N_TOKENS]
                             int S) {
    __shared__ float xs[TM * LSTR];
    __shared__ float ss[NE * LSTR];

    const int t    = threadIdx.x;
    const int tok0 = blockIdx.x * TM;
    const int s    = blockIdx.y;
    const int KC   = DIM / S;        // K-chunk per split
    const int k0b  = s * KC;
    const int nt   = KC / BK;

    const int lr = t >> 4;           // loader row 0..15 (+16m)
    const int lc = (t & 15) << 2;    // loader 16B column
    const int tx = t & 15;           // compute: expert lane
    const int ty = t >> 4;           // compute: token group

    const float* xg = x + (size_t)tok0 * DIM;

    float acc[4][4];
#pragma unroll
    for (int i = 0; i < 4; ++i)
#pragma unroll
        for (int j = 0; j < 4; ++j) acc[i][j] = 0.f;
    float sq[4] = {0.f, 0.f, 0.f, 0.f};

    float4 px[4], ps[4];
#pragma unroll
    for (int m = 0; m < 4; ++m) {
        px[m] = *(const float4*)(xg  + (size_t)(lr + 16 * m) * DIM + k0b + lc);
        ps[m] = *(const float4*)(sig + (size_t)(lr + 16 * m) * DIM + k0b + lc);
    }

    for (int kt = 0; kt < nt; ++kt) {
#pragma unroll
        for (int m = 0; m < 4; ++m) {
            *(float4*)(xs + (lr + 16 * m) * LSTR + lc) = px[m];
            *(float4*)(ss + (lr + 16 * m) * LSTR + lc) = ps[m];
            sq[m] = fmaf(px[m].x, px[m].x, sq[m]);
            sq[m] = fmaf(px[m].y, px[m].y, sq[m]);
            sq[m] = fmaf(px[m].z, px[m].z, sq[m]);
            sq[m] = fmaf(px[m].w, px[m].w, sq[m]);
        }
        __syncthreads();

        if (kt + 1 < nt) {
            const int k0 = k0b + (kt + 1) * BK;
#pragma unroll
            for (int m = 0; m < 4; ++m) {
                px[m] = *(const float4*)(xg  + (size_t)(lr + 16 * m) * DIM + k0 + lc);
                ps[m] = *(const float4*)(sig + (size_t)(lr + 16 * m) * DIM + k0 + lc);
            }
        }

        float tacc[4][4];
#pragma unroll
        for (int i = 0; i < 4; ++i)
#pragma unroll
            for (int j = 0; j < 4; ++j) tacc[i][j] = 0.f;

#pragma unroll
        for (int k4 = 0; k4 < BK; k4 += 4) {
            float4 xv[4], sv[4];
#pragma unroll
            for (int i = 0; i < 4; ++i)
                xv[i] = *(const float4*)(xs + (4 * ty + i) * LSTR + k4);
#pragma unroll
            for (int j = 0; j < 4; ++j)
                sv[j] = *(const float4*)(ss + (tx + 16 * j) * LSTR + k4);
#pragma unroll
            for (int i = 0; i < 4; ++i)
#pragma unroll
                for (int j = 0; j < 4; ++j) {
                    tacc[i][j] = fmaf(xv[i].x, sv[j].x, tacc[i][j]);
                    tacc[i][j] = fmaf(xv[i].y, sv[j].y, tacc[i][j]);
                    tacc[i][j] = fmaf(xv[i].z, sv[j].z, tacc[i][j]);
                    tacc[i][j] = fmaf(xv[i].w, sv[j].w, tacc[i][j]);
                }
        }
#pragma unroll
        for (int i = 0; i < 4; ++i)
#pragma unroll
            for (int j = 0; j < 4; ++j) acc[i][j] += tacc[i][j];
        __syncthreads();
    }

    // partial sumsq: reduce across the 16 lanes sharing each loader row
#pragma unroll
    for (int m = 0; m < 4; ++m) {
        float v = sq[m];
        v += __shfl_xor(v, 1);
        v += __shfl_xor(v, 2);
        v += __shfl_xor(v, 4);
        v += __shfl_xor(v, 8);
        if ((t & 15) == 0)
            SS[(size_t)s * N_TOKENS + tok0 + lr + 16 * m] = v;
    }

    // transpose partial dots into LDS as [e][tok], stride 68 (aligned,
    // conflict-light; once per block)
#pragma unroll
    for (int i = 0; i < 4; ++i)
#pragma unroll
        for (int j = 0; j < 4; ++j)
            xs[(tx + 16 * j) * LSTR + 4 * ty + i] = acc[i][j];
    __syncthreads();

    // coalesced write of P[s][e][tok0..tok0+63]
#pragma unroll
    for (int r = 0; r < 4; ++r) {
        const int idx = r * 256 + t;
        const int e   = idx >> 4;
        const int c   = idx & 15;
        const float4 v = *(const float4*)(xs + e * LSTR + 4 * c);
        *(float4*)(P + ((size_t)(s * NE + e)) * N_TOKENS + tok0 + 4 * c) = v;
    }
}

__launch_bounds__(64)
__global__ void reduce_topk(const float* __restrict__ P,
                            const float* __restrict__ SS,
                            float* __restrict__ outW,
                            float* __restrict__ outI,
                            float* __restrict__ outR,
                            int S) {
    __shared__ float res[16 * LSTR];
    __shared__ float scl[16];

    const int t    = threadIdx.x;
    const int tok0 = blockIdx.x * 16;

    if (t < 16) {
        float q = 0.f;
        for (int s = 0; s < S; ++s)
            q += SS[(size_t)s * N_TOKENS + tok0 + t];
        scl[t] = SCALE / fmaxf(sqrtf(q), EPS);
    }
    __syncthreads();

    const int tl = t & 15;          // token lane
    const int e0 = (t >> 4) * 16;   // expert group
    const float sc = scl[tl];
#pragma unroll
    for (int ei = 0; ei < 16; ++ei) {
        const int e = e0 + ei;
        float a = 0.f;
#pragma unroll 8
        for (int s = 0; s < S; ++s)
            a += P[((size_t)(s * NE + e)) * N_TOKENS + tok0 + tl];
        res[tl * LSTR + e] = a * sc;
    }
    __syncthreads();

    // coalesced resonance write (block's region is contiguous)
    float* dst = outR + (size_t)blockIdx.x * 16 * NE;
#pragma unroll
    for (int r = 0; r < 4; ++r) {
        const int f4 = r * 64 + t;
        const int tk = f4 >> 4;
        const int e4 = (f4 & 15) << 2;
        *(float4*)(dst + (size_t)f4 * 4) = *(const float4*)(res + tk * LSTR + e4);
    }
    __syncthreads();

    // top-8 per token (strict '>' => lowest index on ties, = jax.lax.top_k)
    if (t < 16) {
        float* row = res + t * LSTR;
        const size_t ob = (size_t)(tok0 + t) * TOPK;
#pragma unroll 1
        for (int m = 0; m < TOPK; ++m) {
            float best = -__builtin_inff();
            int bi = 0;
#pragma unroll 1
            for (int e = 0; e < NE; ++e) {
                const float v = row[e];
                if (v > best) { best = v; bi = e; }
            }
            row[bi] = -__builtin_inff();
            outW[ob + m] = log1pf(expf(best));
            outI[ob + m] = (float)bi;
        }
    }
}

// ---- fallback (round-1 monolithic) in case ws_size is too small ----
__launch_bounds__(256)
__global__ void router_mono(const float* __restrict__ x,
                            const float* __restrict__ sig,
                            float* __restrict__ outW,
                            float* __restrict__ outI,
                            float* __restrict__ outR) {
    __shared__ float xs[TM * LSTR];
    __shared__ float ss[NE * LSTR];
    __shared__ float scales[TM];

    const int t    = threadIdx.x;
    const int tok0 = blockIdx.x * TM;
    const int lr = t >> 4;
    const int lc = (t & 15) << 2;
    const int tx = t & 15;
    const int ty = t >> 4;
    const float* xg = x + (size_t)tok0 * DIM;

    float acc[4][4];
#pragma unroll
    for (int i = 0; i < 4; ++i)
#pragma unroll
        for (int j = 0; j < 4; ++j) acc[i][j] = 0.f;
    float sq[4] = {0.f, 0.f, 0.f, 0.f};

    float4 px[4], ps[4];
#pragma unroll
    for (int m = 0; m < 4; ++m) {
        px[m] = *(const float4*)(xg  + (size_t)(lr + 16 * m) * DIM + lc);
        ps[m] = *(const float4*)(sig + (size_t)(lr + 16 * m) * DIM + lc);
    }
    for (int kt = 0; kt < DIM / BK; ++kt) {
#pragma unroll
        for (int m = 0; m < 4; ++m) {
            *(float4*)(xs + (lr + 16 * m) * LSTR + lc) = px[m];
            *(float4*)(ss + (lr + 16 * m) * LSTR + lc) = ps[m];
            sq[m] = fmaf(px[m].x, px[m].x, sq[m]);
            sq[m] = fmaf(px[m].y, px[m].y, sq[m]);
            sq[m] = fmaf(px[m].z, px[m].z, sq[m]);
            sq[m] = fmaf(px[m].w, px[m].w, sq[m]);
        }
        __syncthreads();
        if (kt + 1 < DIM / BK) {
            const int k0 = (kt + 1) * BK;
#pragma unroll
            for (int m = 0; m < 4; ++m) {
                px[m] = *(const float4*)(xg  + (size_t)(lr + 16 * m) * DIM + k0 + lc);
                ps[m] = *(const float4*)(sig + (size_t)(lr + 16 * m) * DIM + k0 + lc);
            }
        }
        float tacc[4][4];
#pragma unroll
        for (int i = 0; i < 4; ++i)
#pragma unroll
            for (int j = 0; j < 4; ++j) tacc[i][j] = 0.f;
#pragma unroll
        for (int k4 = 0; k4 < BK; k4 += 4) {
            float4 xv[4], sv[4];
#pragma unroll
            for (int i = 0; i < 4; ++i)
                xv[i] = *(const float4*)(xs + (4 * ty + i) * LSTR + k4);
#pragma unroll
            for (int j = 0; j < 4; ++j)
                sv[j] = *(const float4*)(ss + (tx + 16 * j) * LSTR + k4);
#pragma unroll
            for (int i = 0; i < 4; ++i)
#pragma unroll
                for (int j = 0; j < 4; ++j) {
                    tacc[i][j] = fmaf(xv[i].x, sv[j].x, tacc[i][j]);
                    tacc[i][j] = fmaf(xv[i].y, sv[j].y, tacc[i][j]);
                    tacc[i][j] = fmaf(xv[i].z, sv[j].z, tacc[i][j]);
                    tacc[i][j] = fmaf(xv[i].w, sv[j].w, tacc[i][j]);
                }
        }
#pragma unroll
        for (int i = 0; i < 4; ++i)
#pragma unroll
            for (int j = 0; j < 4; ++j) acc[i][j] += tacc[i][j];
        __syncthreads();
    }
#pragma unroll
    for (int m = 0; m < 4; ++m) {
        float v = sq[m];
        v += __shfl_xor(v, 1);
        v += __shfl_xor(v, 2);
        v += __shfl_xor(v, 4);
        v += __shfl_xor(v, 8);
        if ((t & 15) == 0) scales[lr + 16 * m] = v;
    }
    __syncthreads();
    if (t < TM) scales[t] = SCALE / fmaxf(sqrtf(scales[t]), EPS);
    __syncthreads();
    float* res = xs;
#pragma unroll
    for (int i = 0; i < 4; ++i) {
        const int tok = 4 * ty + i;
        const float s = scales[tok];
#pragma unroll
        for (int j = 0; j < 4; ++j) {
            const int e = tx + 16 * j;
            const float r = acc[i][j] * s;
            outR[(size_t)(tok0 + tok) * NE + e] = r;
            res[tok * LSTR + e] = r;
        }
    }
    __syncthreads();
    if (t < TM) {
        float* row = res + t * LSTR;
        const size_t ob = (size_t)(tok0 + t) * TOPK;
#pragma unroll 1
        for (int m = 0; m < TOPK; ++m) {
            float best = -__builtin_inff();
            int bi = 0;
#pragma unroll 1
            for (int e = 0; e < NE; ++e) {
                const float v = row[e];
                if (v > best) { best = v; bi = e; }
            }
            row[bi] = -__builtin_inff();
            outW[ob + m] = log1pf(expf(best));
            outI[ob + m] = (float)bi;
        }
    }
}

extern "C" void kernel_launch(void* const* d_in, const int* in_sizes, int n_in,
                              void* d_out, int out_size, void* d_ws, size_t ws_size,
                              hipStream_t stream) {
    const float* x   = (const float*)d_in[0];
    const float* sig = (const float*)d_in[1];
    float* out  = (float*)d_out;
    float* outW = out;
    float* outI = out + (size_t)N_TOKENS * TOPK;
    float* outR = out + (size_t)N_TOKENS * TOPK * 2;

    const size_t per_split_f = (size_t)NE * N_TOKENS + N_TOKENS; // P row + SS row (floats)
    int S = 8;
    while (S > 1 && S * per_split_f * sizeof(float) > ws_size) S >>= 1;

    if (S * per_split_f * sizeof(float) <= ws_size) {
        float* P  = (float*)d_ws;
        float* SS = P + (size_t)S * NE * N_TOKENS;
        dim3 g1(N_TOKENS / TM, S);
        gemm_partial<<<g1, 256, 0, stream>>>(x, sig, P, SS, S);
        reduce_topk<<<N_TOKENS / 16, 64, 0, stream>>>(P, SS, outW, outI, outR, S);
    } else {
        router_mono<<<N_TOKENS / TM, 256, 0, stream>>>(x, sig, outW, outI, outR);
    }
}

// Round 4
// 510.017 us; speedup vs baseline: 1.1909x; 1.1875x over previous
//
#include <hip/hip_runtime.h>
#include <cmath>

// DarwinianRouter: fused L2-normalize + x_norm @ sig^T * 5 + top-8 + softplus.
// Round 4: MFMA path. Rounds 1-3 proved the VALU-GEMM is LDS-pipe-bound at
// ~316us (8 ds_read_b128 per 4096 MACs; invariant to occupancy & conflicts).
// Fix: 3-way bf16 split (h1+h2+h3, ~26 mantissa bits) + 6 MFMA products per
// logical fp32 product => fp32-class accuracy (residual ~2^-26 rel, below the
// fp32 reassociation noise that passed the exact-index check in r1-r3).
// A-frags: direct global fp32 loads + in-reg split (mfma 32x32x16 A/B layout =
// 8 consecutive K per lane = row-major). B-frags: sig pre-split once per
// launch into d_ws (1.5 MB, L2-hot). No LDS in the K-loop at all.

#define N_TOKENS 16384
#define DIM      4096
#define NE       64
#define TOPK     8
#define SCALE    5.0f
#define EPS      1e-12f

typedef short  frag  __attribute__((ext_vector_type(8)));   // 8 bf16 bit-patterns
typedef float  f32x16 __attribute__((ext_vector_type(16))); // 32x32 C/D
typedef int    i32x4 __attribute__((ext_vector_type(4)));

__device__ __forceinline__ void split3(float v, unsigned& h1, unsigned& h2, unsigned& h3) {
    unsigned u  = __builtin_bit_cast(unsigned, v);
    unsigned r1 = (u + 0x7FFFu + ((u >> 16) & 1u)) & 0xFFFF0000u;
    float    d1 = v - __builtin_bit_cast(float, r1);
    unsigned w  = __builtin_bit_cast(unsigned, d1);
    unsigned r2 = (w + 0x7FFFu + ((w >> 16) & 1u)) & 0xFFFF0000u;
    float    d2 = d1 - __builtin_bit_cast(float, r2);
    unsigned z  = __builtin_bit_cast(unsigned, d2);
    unsigned r3 = (z + 0x7FFFu + ((z >> 16) & 1u)) & 0xFFFF0000u;
    h1 = r1 >> 16; h2 = r2 >> 16; h3 = r3 >> 16;
}

// one-time (per launch) sig split: 64x4096 fp32 -> 3 bf16 planes, row-major
__launch_bounds__(256)
__global__ void convert_sig(const float* __restrict__ sig,
                            short* __restrict__ h1,
                            short* __restrict__ h2,
                            short* __restrict__ h3) {
    const int i = (blockIdx.x * 256 + threadIdx.x) * 4;
    const float4 v = *(const float4*)(sig + i);
    const float vs[4] = {v.x, v.y, v.z, v.w};
#pragma unroll
    for (int p = 0; p < 4; ++p) {
        unsigned a, b, c;
        split3(vs[p], a, b, c);
        h1[i + p] = (short)a; h2[i + p] = (short)b; h3[i + p] = (short)c;
    }
}

// grid (N_TOKENS/128, S); block 256 = 4 waves; wave w: tokens tb..tb+31,
// all 64 experts (two 32x32 tiles), K-chunk [s*KC, (s+1)*KC).
__launch_bounds__(256, 4)
__global__ void gemm_mfma(const float* __restrict__ x,
                          const short* __restrict__ sh1,
                          const short* __restrict__ sh2,
                          const short* __restrict__ sh3,
                          float* __restrict__ P,    // [S][NE][N_TOKENS]
                          float* __restrict__ SS,   // [S][N_TOKENS]
                          int S) {
    __shared__ float cstg[4][64 * 36];  // per-wave C transpose (stride 36: 16B-aligned)

    const int t    = threadIdx.x;
    const int lane = t & 63;
    const int w    = t >> 6;
    const int l31  = lane & 31;
    const int half = lane >> 5;

    const int tb = blockIdx.x * 128 + w * 32;      // wave's token base
    const int s  = blockIdx.y;
    const int KC = DIM / S;
    const int k0 = s * KC;
    const int nsteps = KC / 16;

    // A: lane holds tokens row (l31), k = k0 + 16*st + 8*half + [0..7]
    const float* ap = x + (size_t)(tb + l31) * DIM + k0 + 8 * half;
    // B: lane holds expert row (tile*32 + l31), same k pattern
    const size_t boff = (size_t)l31 * DIM + k0 + 8 * half;
    const short* b1p = sh1 + boff;
    const short* b2p = sh2 + boff;
    const short* b3p = sh3 + boff;
    const size_t TILE1 = (size_t)32 * DIM;

    f32x16 c0 = {};   // experts 0..31
    f32x16 c1 = {};   // experts 32..63
    float sq = 0.f;

    float4 av0 = *(const float4*)(ap);
    float4 av1 = *(const float4*)(ap + 4);

#pragma unroll 1
    for (int st = 0; st < nsteps; ++st) {
        // B fragments for this step (L2-hot; issued before the VALU split work)
        const frag b1a = *(const frag*)(b1p);
        const frag b1b = *(const frag*)(b1p + TILE1);
        const frag b2a = *(const frag*)(b2p);
        const frag b2b = *(const frag*)(b2p + TILE1);
        const frag b3a = *(const frag*)(b3p);
        const frag b3b = *(const frag*)(b3p + TILE1);

        // A prefetch for next step (HBM latency cover)
        float4 nv0 = av0, nv1 = av1;
        if (st + 1 < nsteps) {
            nv0 = *(const float4*)(ap + 16);
            nv1 = *(const float4*)(ap + 20);
        }

        // split A into 3 bf16 planes, packed 2 elems/reg; accumulate sumsq
        const float vals[8] = {av0.x, av0.y, av0.z, av0.w, av1.x, av1.y, av1.z, av1.w};
        i32x4 a1i, a2i, a3i;
#pragma unroll
        for (int p = 0; p < 4; ++p) {
            const float v0 = vals[2 * p], v1 = vals[2 * p + 1];
            sq = fmaf(v0, v0, sq);
            sq = fmaf(v1, v1, sq);
            unsigned h10, h20, h30, h11, h21, h31;
            split3(v0, h10, h20, h30);
            split3(v1, h11, h21, h31);
            a1i[p] = (int)(h10 | (h11 << 16));
            a2i[p] = (int)(h20 | (h21 << 16));
            a3i[p] = (int)(h30 | (h31 << 16));
        }
        const frag A1 = __builtin_bit_cast(frag, a1i);
        const frag A2 = __builtin_bit_cast(frag, a2i);
        const frag A3 = __builtin_bit_cast(frag, a3i);

        // 6 products per tile: h1h1 + (h1h2+h2h1) + (h1h3+h3h1+h2h2)
        c0 = __builtin_amdgcn_mfma_f32_32x32x16_bf16(A1, b1a, c0, 0, 0, 0);
        c0 = __builtin_amdgcn_mfma_f32_32x32x16_bf16(A1, b2a, c0, 0, 0, 0);
        c0 = __builtin_amdgcn_mfma_f32_32x32x16_bf16(A2, b1a, c0, 0, 0, 0);
        c0 = __builtin_amdgcn_mfma_f32_32x32x16_bf16(A1, b3a, c0, 0, 0, 0);
        c0 = __builtin_amdgcn_mfma_f32_32x32x16_bf16(A3, b1a, c0, 0, 0, 0);
        c0 = __builtin_amdgcn_mfma_f32_32x32x16_bf16(A2, b2a, c0, 0, 0, 0);

        c1 = __builtin_amdgcn_mfma_f32_32x32x16_bf16(A1, b1b, c1, 0, 0, 0);
        c1 = __builtin_amdgcn_mfma_f32_32x32x16_bf16(A1, b2b, c1, 0, 0, 0);
        c1 = __builtin_amdgcn_mfma_f32_32x32x16_bf16(A2, b1b, c1, 0, 0, 0);
        c1 = __builtin_amdgcn_mfma_f32_32x32x16_bf16(A1, b3b, c1, 0, 0, 0);
        c1 = __builtin_amdgcn_mfma_f32_32x32x16_bf16(A3, b1b, c1, 0, 0, 0);
        c1 = __builtin_amdgcn_mfma_f32_32x32x16_bf16(A2, b2b, c1, 0, 0, 0);

        av0 = nv0; av1 = nv1;
        ap += 16; b1p += 16; b2p += 16; b3p += 16;
    }

    // per-token partial sumsq: lanes l and l+32 hold the same token row
    sq += __shfl_xor(sq, 32);
    if (lane < 32)
        SS[(size_t)s * N_TOKENS + tb + l31] = sq;

    // C epilogue: transpose to [e][tok] in per-wave LDS, then coalesced P write
    float* stg = cstg[w];
#pragma unroll
    for (int r = 0; r < 16; ++r) {
        const int row = (r & 3) + 8 * (r >> 2) + 4 * half;  // token within 32
        stg[l31 * 36 + row]        = c0[r];
        stg[(32 + l31) * 36 + row] = c1[r];
    }
    __syncthreads();
    {
        const int e = lane;  // 0..63
        float* dst = P + ((size_t)(s * NE + e)) * N_TOKENS + tb;
        const float* src = stg + e * 36;
#pragma unroll
        for (int j = 0; j < 8; ++j)
            *(float4*)(dst + 4 * j) = *(const float4*)(src + 4 * j);
    }
}

__launch_bounds__(256)
__global__ void reduce_topk(const float* __restrict__ P,
                            const float* __restrict__ SS,
                            float* __restrict__ outW,
                            float* __restrict__ outI,
                            float* __restrict__ outR,
                            int S) {
    __shared__ float res[16 * 68];
    __shared__ float scl[16];

    const int t    = threadIdx.x;
    const int tok0 = blockIdx.x * 16;

    if (t < 16) {
        float q = 0.f;
        for (int s = 0; s < S; ++s)
            q += SS[(size_t)s * N_TOKENS + tok0 + t];
        scl[t] = SCALE / fmaxf(sqrtf(q), EPS);
    }
    __syncthreads();

    const int tl = t & 15;
    const int eg = t >> 4;          // 0..15
#pragma unroll
    for (int q = 0; q < 4; ++q) {
        const int e = eg * 4 + q;
        float a = 0.f;
#pragma unroll 1
        for (int s = 0; s < S; ++s)
            a += P[((size_t)(s * NE + e)) * N_TOKENS + tok0 + tl];
        res[tl * 68 + e] = a * scl[tl];
    }
    __syncthreads();

    // coalesced resonance write
    {
        const int tk = t >> 4, e4 = (t & 15) * 4;
        *(float4*)(outR + (size_t)(tok0 + tk) * NE + e4) =
            *(const float4*)(res + tk * 68 + e4);
    }
    __syncthreads();

    // top-8 per token (strict '>' => lowest index on ties, = jax.lax.top_k)
    if (t < 16) {
        float* row = res + t * 68;
        const size_t ob = (size_t)(tok0 + t) * TOPK;
#pragma unroll 1
        for (int m = 0; m < TOPK; ++m) {
            float best = -__builtin_inff();
            int bi = 0;
#pragma unroll 1
            for (int e = 0; e < NE; ++e) {
                const float v = row[e];
                if (v > best) { best = v; bi = e; }
            }
            row[bi] = -__builtin_inff();
            outW[ob + m] = log1pf(expf(best));
            outI[ob + m] = (float)bi;
        }
    }
}

extern "C" void kernel_launch(void* const* d_in, const int* in_sizes, int n_in,
                              void* d_out, int out_size, void* d_ws, size_t ws_size,
                              hipStream_t stream) {
    const float* x   = (const float*)d_in[0];
    const float* sig = (const float*)d_in[1];
    float* out  = (float*)d_out;
    float* outW = out;
    float* outI = out + (size_t)N_TOKENS * TOPK;
    float* outR = out + (size_t)N_TOKENS * TOPK * 2;

    const size_t SIGE = (size_t)NE * DIM;           // 262144 elems
    // ws layout: P [S][NE][N_TOKENS] f32 | SS [S][N_TOKENS] f32 | sh1,sh2,sh3 bf16
    int S = 8;
    auto need = [&](int s) {
        return ((size_t)s * NE * N_TOKENS + (size_t)s * N_TOKENS) * 4 + 3 * SIGE * 2;
    };
    while (S > 1 && need(S) > ws_size) S >>= 1;

    float* P  = (float*)d_ws;
    float* SS = P + (size_t)S * NE * N_TOKENS;
    short* sh1 = (short*)(SS + (size_t)S * N_TOKENS);
    short* sh2 = sh1 + SIGE;
    short* sh3 = sh2 + SIGE;

    convert_sig<<<SIGE / (256 * 4), 256, 0, stream>>>(sig, sh1, sh2, sh3);
    dim3 g1(N_TOKENS / 128, S);
    gemm_mfma<<<g1, 256, 0, stream>>>(x, sh1, sh2, sh3, P, SS, S);
    reduce_topk<<<N_TOKENS / 16, 256, 0, stream>>>(P, SS, outW, outI, outR, S);
}